// Round 7
// baseline (229.191 us; speedup 1.0000x reference)
//
#include <hip/hip_runtime.h>

// Causal GQA attention prefill, fp32 in/out, MFMA 32x32x16 bf16 compute.
// S=2048, H=32, KVH=8 (rep=4), D=128.
// Round 7 = round 6 with the scratch-spill fixed:
//   Round 6's union-based fragment assembly (PCHUNK / qf) defeated SROA ->
//   alloca in scratch -> WRITE_SIZE 46->116 MB and +18us. All hot-loop
//   fragment packing is now pure SSA: uint4 ext-vector + __builtin_bit_cast,
//   P-chunks built by a by-value inline function, no unions, no local arrays
//   indexed in the tile loop. BAR() lgkm-only barrier, complementary pairing,
//   base-2 softmax, in-register P transform all kept from round 6.

#define SEQ   2048
#define NH    32
#define NKVH  8
#define HD    128
#define BQ    128
#define BK    64
#define KSS   136   // ks stride (ushort)
#define VTS   72    // vt stride (ushort)
#define PSS   72    // (fallback kernel only)
#define SCALE 0.08838834764831845f
#define QSCL  (0.08838834764831845f * 1.4426950408889634f)   // SCALE*log2(e)

#define KB_ELEMS (SEQ * NKVH * HD)
#define WS_NEED  (2u * KB_ELEMS * 2u)

// lgkm-only barrier: vmcnt (global prefetch) stays outstanding across it.
#define BAR() asm volatile("s_waitcnt lgkmcnt(0)\n\ts_barrier" ::: "memory")

typedef __attribute__((ext_vector_type(8)))  short short8;
typedef __attribute__((ext_vector_type(16))) float float16;
typedef __attribute__((ext_vector_type(4)))  unsigned int uint4v;

__device__ __forceinline__ unsigned short f2bf(float f) {
    union { float f; unsigned int i; } x; x.f = f;
    unsigned int r = x.i + 0x7fffu + ((x.i >> 16) & 1u);   // RNE
    return (unsigned short)(r >> 16);
}
__device__ __forceinline__ unsigned int f2bf2(float lo, float hi) {
    return (unsigned int)f2bf(lo) | ((unsigned int)f2bf(hi) << 16);
}

// Build one PV A-fragment (keys 16c..16c+15 viewed from this lane) from the
// C-layout exp'd scores. Pure SSA: by-value vector, constant c, bit_cast out.
__device__ __forceinline__ short8 pchunk(float16 st, int c, int half) {
    const unsigned L0 = f2bf2(st[8 * c + 0], st[8 * c + 1]);
    const unsigned L1 = f2bf2(st[8 * c + 2], st[8 * c + 3]);
    const unsigned H0 = f2bf2(st[8 * c + 4], st[8 * c + 5]);
    const unsigned H1 = f2bf2(st[8 * c + 6], st[8 * c + 7]);
    const unsigned S0 = half ? L0 : H0;
    const unsigned S1 = half ? L1 : H1;
    const unsigned R0 = (unsigned)__shfl_xor((int)S0, 32, 64);
    const unsigned R1 = (unsigned)__shfl_xor((int)S1, 32, 64);
    uint4v r;
    r.x = half ? R0 : L0;
    r.y = half ? R1 : L1;
    r.z = half ? H0 : R0;
    r.w = half ? H1 : R1;
    return __builtin_bit_cast(short8, r);
}

// ---- prep: K fp32 -> bf16, natural [s][kvh][d] ----
__global__ __launch_bounds__(256)
void cvt_k(const float* __restrict__ k, unsigned short* __restrict__ kb)
{
    const int i = (blockIdx.x * 256 + threadIdx.x) * 4;
    const float4 a = *(const float4*)(k + i);
    uint2 o; o.x = f2bf2(a.x, a.y); o.y = f2bf2(a.z, a.w);
    *(uint2*)(kb + i) = o;
}

// ---- prep: V fp32 -> bf16 transposed tiles vtw[kvh][jt][d][key64] ----
__global__ __launch_bounds__(256)
void cvt_v(const float* __restrict__ v, unsigned short* __restrict__ vtw)
{
    __shared__ unsigned short tl[HD * VTS];
    const int t   = threadIdx.x;
    const int jt  = blockIdx.x & 31;
    const int kvh = blockIdx.x >> 5;
    const int dp  = (t & 63) * 2;
    const int k0  = t >> 6;
    #pragma unroll
    for (int r = 0; r < 16; ++r) {
        const int key = k0 + r * 4;
        const float2 a =
            *(const float2*)(v + ((size_t)(jt * 64 + key) * NKVH + kvh) * HD + dp);
        tl[dp * VTS + key]       = f2bf(a.x);
        tl[(dp + 1) * VTS + key] = f2bf(a.y);
    }
    __syncthreads();
    unsigned short* dst = vtw + (size_t)(kvh * 32 + jt) * HD * 64;
    const int c  = t & 7;
    const int d0 = t >> 3;
    #pragma unroll
    for (int r = 0; r < 4; ++r) {
        const int d = d0 + r * 32;
        *(uint4*)(dst + d * 64 + c * 8) = *(const uint4*)&tl[d * VTS + c * 8];
    }
}

// ---- main ----
__global__ __launch_bounds__(256, 2)
void attn_fwd2(const float* __restrict__ q,
               const unsigned short* __restrict__ kb,
               const unsigned short* __restrict__ vtw,
               float* __restrict__ out)
{
    __shared__ unsigned short ks[BK * KSS];
    __shared__ unsigned short vt[HD * VTS];
    __shared__ float          alf[4][32];

    const int t    = threadIdx.x;
    const int w    = t >> 6;
    const int lane = t & 63;
    const int ln   = lane & 31;
    const int half = lane >> 5;

    const int pair = blockIdx.x & 255;
    const int late = blockIdx.x >> 8;
    const int h    = pair & 31;
    const int px   = pair >> 5;
    const int bx   = late ? (15 - px) : px;
    const int kvh  = h >> 2;
    const int q0   = bx * BQ;
    const int wq0  = q0 + w * 32;
    const int qrow = wq0 + ln;
    const int ntiles = q0 / BK + 2;
    const int wqmax  = wq0 + 31;

    const int skey = t >> 2, sc = t & 3;
    const int vc = t & 7, vd0 = t >> 3;
    const unsigned short* vtile0 = vtw + (size_t)(kvh * 32) * HD * 64;

    // ---- Q fragments, pre-scaled by SCALE*log2e (SSA, bit_cast) ----
    short8 qf[8];
    {
        const float* qr = q + ((size_t)qrow * NH + h) * HD;
        #pragma unroll
        for (int k0 = 0; k0 < 8; ++k0) {
            const float* p4 = qr + k0 * 16 + half * 8;
            const float4 a = *(const float4*)(p4);
            const float4 b = *(const float4*)(p4 + 4);
            uint4v uu;
            uu.x = f2bf2(a.x * QSCL, a.y * QSCL);
            uu.y = f2bf2(a.z * QSCL, a.w * QSCL);
            uu.z = f2bf2(b.x * QSCL, b.y * QSCL);
            uu.w = f2bf2(b.z * QSCL, b.w * QSCL);
            qf[k0] = __builtin_bit_cast(short8, uu);
        }
    }

    float16 o0, o1, o2, o3;
    #pragma unroll
    for (int i = 0; i < 16; ++i) { o0[i] = 0.f; o1[i] = 0.f; o2[i] = 0.f; o3[i] = 0.f; }
    float m_run = -1e30f, l_run = 0.f;

    // ---- prefetch tile 0 into registers ----
    uint4 kpre[4], vpre[4];
    {
        const unsigned short* krow = kb + ((size_t)skey * NKVH + kvh) * HD + sc * 8;
        #pragma unroll
        for (int r = 0; r < 4; ++r) kpre[r] = *(const uint4*)(krow + r * 32);
        #pragma unroll
        for (int r = 0; r < 4; ++r)
            vpre[r] = *(const uint4*)(vtile0 + (size_t)t * 8 + r * 2048);
    }

    for (int it = 0; it < ntiles; ++it) {
        const int j0 = it * BK;
        BAR();   // previous tile's fragment reads done (lgkm only)

        #pragma unroll
        for (int r = 0; r < 4; ++r)
            *(uint4*)&ks[skey * KSS + sc * 8 + r * 32] = kpre[r];
        #pragma unroll
        for (int r = 0; r < 4; ++r)
            *(uint4*)&vt[(vd0 + r * 32) * VTS + vc * 8] = vpre[r];

        // prefetch next tile; vmcnt floats across BAR into next iteration
        if (it + 1 < ntiles) {
            const int j1 = j0 + BK;
            const unsigned short* krow =
                kb + ((size_t)(j1 + skey) * NKVH + kvh) * HD + sc * 8;
            #pragma unroll
            for (int r = 0; r < 4; ++r) kpre[r] = *(const uint4*)(krow + r * 32);
            const unsigned short* vtile = vtile0 + (size_t)(it + 1) * HD * 64;
            #pragma unroll
            for (int r = 0; r < 4; ++r)
                vpre[r] = *(const uint4*)(vtile + (size_t)t * 8 + r * 2048);
        }
        BAR();

        if (j0 > wqmax) continue;

        // ---- S^T = K Q^T (scores already in log2 units) ----
        float16 st0, st1;
        #pragma unroll
        for (int i = 0; i < 16; ++i) { st0[i] = 0.f; st1[i] = 0.f; }
        #pragma unroll
        for (int k0 = 0; k0 < 8; ++k0) {
            const short8 a0 = *(const short8*)&ks[ln * KSS + k0 * 16 + half * 8];
            const short8 a1 = *(const short8*)&ks[(32 + ln) * KSS + k0 * 16 + half * 8];
            st0 = __builtin_amdgcn_mfma_f32_32x32x16_bf16(a0, qf[k0], st0, 0, 0, 0);
            st1 = __builtin_amdgcn_mfma_f32_32x32x16_bf16(a1, qf[k0], st1, 0, 0, 0);
        }

        // ---- mask + per-lane online softmax (base-2) ----
        const bool need_mask = (j0 + BK - 1) > wq0;
        float mt = -1e30f;
        if (need_mask) {
            #pragma unroll
            for (int r = 0; r < 16; ++r) {
                const int kl = (r & 3) + 8 * (r >> 2) + 4 * half;
                if (j0 + kl > qrow)      st0[r] = -1e30f;
                if (j0 + 32 + kl > qrow) st1[r] = -1e30f;
                mt = fmaxf(mt, fmaxf(st0[r], st1[r]));
            }
        } else {
            #pragma unroll
            for (int r = 0; r < 16; ++r)
                mt = fmaxf(mt, fmaxf(st0[r], st1[r]));
        }
        mt = fmaxf(mt, __shfl_xor(mt, 32, 64));
        const float mn = fmaxf(m_run, mt);
        float sm = 0.f;
        #pragma unroll
        for (int r = 0; r < 16; ++r) {
            const float e0 = exp2f(st0[r] - mn);
            const float e1 = exp2f(st1[r] - mn);
            st0[r] = e0; st1[r] = e1;
            sm += e0 + e1;
        }
        sm += __shfl_xor(sm, 32, 64);
        const float alpha = exp2f(m_run - mn);
        m_run = mn;
        l_run = l_run * alpha + sm;
        if (half == 0) alf[w][ln] = alpha;

        // ---- P C-layout -> A-layout in-register (pure SSA) ----
        const short8 p0 = pchunk(st0, 0, half);
        const short8 p1 = pchunk(st0, 1, half);
        const short8 p2 = pchunk(st1, 0, half);
        const short8 p3 = pchunk(st1, 1, half);

        // ---- rescale O ----
        #pragma unroll
        for (int r = 0; r < 16; ++r) {
            const int rl = (r & 3) + 8 * (r >> 2) + 4 * half;
            const float ar = alf[w][rl];
            o0[r] *= ar; o1[r] *= ar; o2[r] *= ar; o3[r] *= ar;
        }

        // ---- PV: 4 key-chunks x 4 d-chunks, manual unroll (no arrays) ----
        #define PVSTEP(pp, kc)                                                        \
        {                                                                             \
            const short8 bv0 = *(const short8*)&vt[(ln)      * VTS + (kc) * 16 + half * 8]; \
            const short8 bv1 = *(const short8*)&vt[(32 + ln) * VTS + (kc) * 16 + half * 8]; \
            const short8 bv2 = *(const short8*)&vt[(64 + ln) * VTS + (kc) * 16 + half * 8]; \
            const short8 bv3 = *(const short8*)&vt[(96 + ln) * VTS + (kc) * 16 + half * 8]; \
            o0 = __builtin_amdgcn_mfma_f32_32x32x16_bf16(pp, bv0, o0, 0, 0, 0);       \
            o1 = __builtin_amdgcn_mfma_f32_32x32x16_bf16(pp, bv1, o1, 0, 0, 0);       \
            o2 = __builtin_amdgcn_mfma_f32_32x32x16_bf16(pp, bv2, o2, 0, 0, 0);       \
            o3 = __builtin_amdgcn_mfma_f32_32x32x16_bf16(pp, bv3, o3, 0, 0, 0);       \
        }
        PVSTEP(p0, 0)
        PVSTEP(p1, 1)
        PVSTEP(p2, 2)
        PVSTEP(p3, 3)
        #undef PVSTEP
    }

    // ---- epilogue ----
    if (half == 0) alf[w][ln] = l_run;
    __builtin_amdgcn_s_waitcnt(0);
    #pragma unroll
    for (int r = 0; r < 16; ++r) {
        const int rl = (r & 3) + 8 * (r >> 2) + 4 * half;
        const float inv = 1.f / alf[w][rl];
        float* orow = out + ((size_t)(wq0 + rl) * NH + h) * HD;
        orow[ln]      = o0[r] * inv;
        orow[32 + ln] = o1[r] * inv;
        orow[64 + ln] = o2[r] * inv;
        orow[96 + ln] = o3[r] * inv;
    }
}

// ---- fallback (round-4 kernel, no workspace needed) ----
__global__ __launch_bounds__(256, 2)
void attn_fwd_fb(const float* __restrict__ q,
                 const float* __restrict__ k,
                 const float* __restrict__ v,
                 float* __restrict__ out)
{
    __shared__ unsigned short ks[BK * KSS];
    __shared__ unsigned short vt[HD * VTS];
    __shared__ unsigned short ps[4][32 * PSS];
    __shared__ float          alf[4][32];

    const int t    = threadIdx.x;
    const int w    = t >> 6;
    const int lane = t & 63;
    const int ln   = lane & 31;
    const int half = lane >> 5;
    const int h    = blockIdx.y;
    const int kvh  = h >> 2;
    const int q0   = blockIdx.x * BQ;
    const int wq0  = q0 + w * 32;
    const int qrow = wq0 + ln;

    short8 qf[8];
    {
        const float* qr = q + ((size_t)qrow * NH + h) * HD;
        #pragma unroll
        for (int k0 = 0; k0 < 8; ++k0) {
            const float* p4 = qr + k0 * 16 + half * 8;
            const float4 a = *(const float4*)(p4);
            const float4 b = *(const float4*)(p4 + 4);
            uint4v uu;
            uu.x = f2bf2(a.x, a.y);
            uu.y = f2bf2(a.z, a.w);
            uu.z = f2bf2(b.x, b.y);
            uu.w = f2bf2(b.z, b.w);
            qf[k0] = __builtin_bit_cast(short8, uu);
        }
    }

    float16 o0, o1, o2, o3;
    #pragma unroll
    for (int i = 0; i < 16; ++i) { o0[i] = 0.f; o1[i] = 0.f; o2[i] = 0.f; o3[i] = 0.f; }
    float m_run = -1e30f, l_run = 0.f;
    const int ntiles = (q0 + BQ) / BK;
    const int wqmax  = wq0 + 31;

    for (int it = 0; it < ntiles; ++it) {
        const int j0 = it * BK;
        __syncthreads();
        {
            const int key = t >> 2;
            const int db  = (t & 3) * 4;
            const float* kr = k + ((size_t)(j0 + key) * NKVH + kvh) * HD;
            #pragma unroll
            for (int r2 = 0; r2 < 8; ++r2) {
                const int d = db + r2 * 16;
                const float4 a = *(const float4*)(kr + d);
                *(unsigned int*)&ks[key * KSS + d]     = f2bf2(a.x, a.y);
                *(unsigned int*)&ks[key * KSS + d + 2] = f2bf2(a.z, a.w);
            }
        }
        {
            const int kp = (t & 31) * 2;
            const int db = (t >> 5) * 4;
            const float* vr0 = v + ((size_t)(j0 + kp) * NKVH + kvh) * HD;
            const float* vr1 = vr0 + NKVH * HD;
            #pragma unroll
            for (int r2 = 0; r2 < 4; ++r2) {
                const int d = db + r2 * 32;
                const float4 a = *(const float4*)(vr0 + d);
                const float4 b = *(const float4*)(vr1 + d);
                *(unsigned int*)&vt[(d + 0) * VTS + kp] = f2bf2(a.x, b.x);
                *(unsigned int*)&vt[(d + 1) * VTS + kp] = f2bf2(a.y, b.y);
                *(unsigned int*)&vt[(d + 2) * VTS + kp] = f2bf2(a.z, b.z);
                *(unsigned int*)&vt[(d + 3) * VTS + kp] = f2bf2(a.w, b.w);
            }
        }
        __syncthreads();
        if (j0 > wqmax) continue;

        float16 st0, st1;
        #pragma unroll
        for (int i = 0; i < 16; ++i) { st0[i] = 0.f; st1[i] = 0.f; }
        #pragma unroll
        for (int k0 = 0; k0 < 8; ++k0) {
            const short8 a0 = *(const short8*)&ks[ln * KSS + k0 * 16 + half * 8];
            const short8 a1 = *(const short8*)&ks[(32 + ln) * KSS + k0 * 16 + half * 8];
            st0 = __builtin_amdgcn_mfma_f32_32x32x16_bf16(a0, qf[k0], st0, 0, 0, 0);
            st1 = __builtin_amdgcn_mfma_f32_32x32x16_bf16(a1, qf[k0], st1, 0, 0, 0);
        }
        const bool need_mask = (j0 + BK - 1) > wq0;
        float mt = -1e30f;
        #pragma unroll
        for (int r = 0; r < 16; ++r) {
            const int kl = (r & 3) + 8 * (r >> 2) + 4 * half;
            float a0 = st0[r] * SCALE;
            float a1 = st1[r] * SCALE;
            if (need_mask) {
                if (j0 + kl > qrow)      a0 = -1e30f;
                if (j0 + 32 + kl > qrow) a1 = -1e30f;
            }
            st0[r] = a0; st1[r] = a1;
            mt = fmaxf(mt, fmaxf(a0, a1));
        }
        mt = fmaxf(mt, __shfl_xor(mt, 32, 64));
        const float mn = fmaxf(m_run, mt);
        float sm = 0.f;
        #pragma unroll
        for (int r = 0; r < 16; ++r) {
            const float e0 = __expf(st0[r] - mn);
            const float e1 = __expf(st1[r] - mn);
            st0[r] = e0; st1[r] = e1;
            sm += e0 + e1;
        }
        sm += __shfl_xor(sm, 32, 64);
        const float alpha = __expf(m_run - mn);
        m_run = mn;
        l_run = l_run * alpha + sm;

        unsigned short* psw = ps[w];
        #pragma unroll
        for (int r = 0; r < 16; r += 2) {
            const int kl = (r & 3) + 8 * (r >> 2) + 4 * half;
            *(unsigned int*)&psw[ln * PSS + kl]      = f2bf2(st0[r], st0[r + 1]);
            *(unsigned int*)&psw[ln * PSS + 32 + kl] = f2bf2(st1[r], st1[r + 1]);
        }
        if (half == 0) alf[w][ln] = alpha;
        #pragma unroll
        for (int r = 0; r < 16; ++r) {
            const int rl = (r & 3) + 8 * (r >> 2) + 4 * half;
            const float ar = alf[w][rl];
            o0[r] *= ar; o1[r] *= ar; o2[r] *= ar; o3[r] *= ar;
        }
        short8 af[4];
        #pragma unroll
        for (int kc = 0; kc < 4; ++kc)
            af[kc] = *(const short8*)&psw[ln * PSS + kc * 16 + half * 8];
        #pragma unroll
        for (int kc = 0; kc < 4; ++kc) {
            const short8 bv0 = *(const short8*)&vt[(ln)      * VTS + kc * 16 + half * 8];
            const short8 bv1 = *(const short8*)&vt[(32 + ln) * VTS + kc * 16 + half * 8];
            const short8 bv2 = *(const short8*)&vt[(64 + ln) * VTS + kc * 16 + half * 8];
            const short8 bv3 = *(const short8*)&vt[(96 + ln) * VTS + kc * 16 + half * 8];
            o0 = __builtin_amdgcn_mfma_f32_32x32x16_bf16(af[kc], bv0, o0, 0, 0, 0);
            o1 = __builtin_amdgcn_mfma_f32_32x32x16_bf16(af[kc], bv1, o1, 0, 0, 0);
            o2 = __builtin_amdgcn_mfma_f32_32x32x16_bf16(af[kc], bv2, o2, 0, 0, 0);
            o3 = __builtin_amdgcn_mfma_f32_32x32x16_bf16(af[kc], bv3, o3, 0, 0, 0);
        }
    }

    if (half == 0) alf[w][ln] = l_run;
    __builtin_amdgcn_s_waitcnt(0);
    #pragma unroll
    for (int r = 0; r < 16; ++r) {
        const int rl = (r & 3) + 8 * (r >> 2) + 4 * half;
        const float inv = 1.f / alf[w][rl];
        float* orow = out + ((size_t)(wq0 + rl) * NH + h) * HD;
        orow[ln]      = o0[r] * inv;
        orow[32 + ln] = o1[r] * inv;
        orow[64 + ln] = o2[r] * inv;
        orow[96 + ln] = o3[r] * inv;
    }
}

extern "C" void kernel_launch(void* const* d_in, const int* in_sizes, int n_in,
                              void* d_out, int out_size, void* d_ws, size_t ws_size,
                              hipStream_t stream) {
    const float* q = (const float*)d_in[0];
    const float* k = (const float*)d_in[1];
    const float* v = (const float*)d_in[2];
    float* out = (float*)d_out;
    if (ws_size >= (size_t)WS_NEED) {
        unsigned short* kb  = (unsigned short*)d_ws;
        unsigned short* vtw = kb + KB_ELEMS;
        cvt_k<<<KB_ELEMS / (256 * 4), 256, 0, stream>>>(k, kb);
        cvt_v<<<NKVH * 32, 256, 0, stream>>>(v, vtw);
        attn_fwd2<<<512, 256, 0, stream>>>(q, kb, vtw, out);
    } else {
        attn_fwd_fb<<<dim3(SEQ / BQ, NH), 256, 0, stream>>>(q, k, v, out);
    }
}

// Round 8
// 215.681 us; speedup vs baseline: 1.0626x; 1.0626x over previous
//
#include <hip/hip_runtime.h>

// Causal GQA attention prefill, fp32 in/out, MFMA 32x32x16 bf16 compute.
// S=2048, H=32, KVH=8 (rep=4), D=128.
// Round 8: back to plain __syncthreads() (round 6/7's asm-"memory" BAR()
//   forced scratch flushes: WRITE_SIZE 46->117MB), with the vmcnt-drain
//   stall fixed STRUCTURALLY: double-buffered LDS, ONE barrier per tile.
//   Loads for tile it+2 are issued right after writing tile it+1 to LDS,
//   so the barrier's vmcnt drain lands a full compute phase later.

#define SEQ   2048
#define NH    32
#define NKVH  8
#define HD    128
#define BQ    128
#define BK    64
#define KSS   136   // ks stride (ushort)
#define VTS   72    // vt stride (ushort)
#define PSS   72    // (fallback kernel only)
#define SCALE 0.08838834764831845f
#define QSCL  (0.08838834764831845f * 1.4426950408889634f)   // SCALE*log2(e)

#define KB_ELEMS (SEQ * NKVH * HD)
#define WS_NEED  (2u * KB_ELEMS * 2u)

typedef __attribute__((ext_vector_type(8)))  short short8;
typedef __attribute__((ext_vector_type(16))) float float16;
typedef __attribute__((ext_vector_type(4)))  unsigned int uint4v;

__device__ __forceinline__ unsigned short f2bf(float f) {
    union { float f; unsigned int i; } x; x.f = f;
    unsigned int r = x.i + 0x7fffu + ((x.i >> 16) & 1u);   // RNE
    return (unsigned short)(r >> 16);
}
__device__ __forceinline__ unsigned int f2bf2(float lo, float hi) {
    return (unsigned int)f2bf(lo) | ((unsigned int)f2bf(hi) << 16);
}

// PV A-fragment (keys 16c..16c+15) from C-layout exp'd scores, pure SSA.
__device__ __forceinline__ short8 pchunk(float16 st, int c, int half) {
    const unsigned L0 = f2bf2(st[8 * c + 0], st[8 * c + 1]);
    const unsigned L1 = f2bf2(st[8 * c + 2], st[8 * c + 3]);
    const unsigned H0 = f2bf2(st[8 * c + 4], st[8 * c + 5]);
    const unsigned H1 = f2bf2(st[8 * c + 6], st[8 * c + 7]);
    const unsigned S0 = half ? L0 : H0;
    const unsigned S1 = half ? L1 : H1;
    const unsigned R0 = (unsigned)__shfl_xor((int)S0, 32, 64);
    const unsigned R1 = (unsigned)__shfl_xor((int)S1, 32, 64);
    uint4v r;
    r.x = half ? R0 : L0;
    r.y = half ? R1 : L1;
    r.z = half ? H0 : R0;
    r.w = half ? H1 : R1;
    return __builtin_bit_cast(short8, r);
}

// ---- prep: K fp32 -> bf16, natural [s][kvh][d] ----
__global__ __launch_bounds__(256)
void cvt_k(const float* __restrict__ k, unsigned short* __restrict__ kb)
{
    const int i = (blockIdx.x * 256 + threadIdx.x) * 4;
    const float4 a = *(const float4*)(k + i);
    uint2 o; o.x = f2bf2(a.x, a.y); o.y = f2bf2(a.z, a.w);
    *(uint2*)(kb + i) = o;
}

// ---- prep: V fp32 -> bf16 transposed tiles vtw[kvh][jt][d][key64] ----
__global__ __launch_bounds__(256)
void cvt_v(const float* __restrict__ v, unsigned short* __restrict__ vtw)
{
    __shared__ unsigned short tl[HD * VTS];
    const int t   = threadIdx.x;
    const int jt  = blockIdx.x & 31;
    const int kvh = blockIdx.x >> 5;
    const int dp  = (t & 63) * 2;
    const int k0  = t >> 6;
    #pragma unroll
    for (int r = 0; r < 16; ++r) {
        const int key = k0 + r * 4;
        const float2 a =
            *(const float2*)(v + ((size_t)(jt * 64 + key) * NKVH + kvh) * HD + dp);
        tl[dp * VTS + key]       = f2bf(a.x);
        tl[(dp + 1) * VTS + key] = f2bf(a.y);
    }
    __syncthreads();
    unsigned short* dst = vtw + (size_t)(kvh * 32 + jt) * HD * 64;
    const int c  = t & 7;
    const int d0 = t >> 3;
    #pragma unroll
    for (int r = 0; r < 4; ++r) {
        const int d = d0 + r * 32;
        *(uint4*)(dst + d * 64 + c * 8) = *(const uint4*)&tl[d * VTS + c * 8];
    }
}

// ---- main ----
__global__ __launch_bounds__(256, 2)
void attn_fwd2(const float* __restrict__ q,
               const unsigned short* __restrict__ kb,
               const unsigned short* __restrict__ vtw,
               float* __restrict__ out)
{
    __shared__ unsigned short ks[2][BK * KSS];
    __shared__ unsigned short vt[2][HD * VTS];
    __shared__ float          alf[4][32];

    const int t    = threadIdx.x;
    const int w    = t >> 6;
    const int lane = t & 63;
    const int ln   = lane & 31;
    const int half = lane >> 5;

    const int pair = blockIdx.x & 255;
    const int late = blockIdx.x >> 8;
    const int h    = pair & 31;
    const int px   = pair >> 5;
    const int bx   = late ? (15 - px) : px;
    const int kvh  = h >> 2;
    const int q0   = bx * BQ;
    const int wq0  = q0 + w * 32;
    const int qrow = wq0 + ln;
    const int ntiles = q0 / BK + 2;
    const int wqmax  = wq0 + 31;

    const int skey = t >> 2, sc = t & 3;
    const int vc = t & 7, vd0 = t >> 3;
    const unsigned short* vtile0 = vtw + (size_t)(kvh * 32) * HD * 64;

    // ---- Q fragments, pre-scaled by SCALE*log2e ----
    short8 qf[8];
    {
        const float* qr = q + ((size_t)qrow * NH + h) * HD;
        #pragma unroll
        for (int k0 = 0; k0 < 8; ++k0) {
            const float* p4 = qr + k0 * 16 + half * 8;
            const float4 a = *(const float4*)(p4);
            const float4 b = *(const float4*)(p4 + 4);
            uint4v uu;
            uu.x = f2bf2(a.x * QSCL, a.y * QSCL);
            uu.y = f2bf2(a.z * QSCL, a.w * QSCL);
            uu.z = f2bf2(b.x * QSCL, b.y * QSCL);
            uu.w = f2bf2(b.z * QSCL, b.w * QSCL);
            qf[k0] = __builtin_bit_cast(short8, uu);
        }
    }

    float16 o0, o1, o2, o3;
    #pragma unroll
    for (int i = 0; i < 16; ++i) { o0[i] = 0.f; o1[i] = 0.f; o2[i] = 0.f; o3[i] = 0.f; }
    float m_run = -1e30f, l_run = 0.f;

    // ---- preamble: tile0 -> buf0; prefetch tile1 -> regs ----
    uint4 kpre[4], vpre[4];
    {
        const unsigned short* krow = kb + ((size_t)skey * NKVH + kvh) * HD + sc * 8;
        #pragma unroll
        for (int r = 0; r < 4; ++r) kpre[r] = *(const uint4*)(krow + r * 32);
        #pragma unroll
        for (int r = 0; r < 4; ++r)
            vpre[r] = *(const uint4*)(vtile0 + (size_t)t * 8 + r * 2048);
        #pragma unroll
        for (int r = 0; r < 4; ++r)
            *(uint4*)&ks[0][skey * KSS + sc * 8 + r * 32] = kpre[r];
        #pragma unroll
        for (int r = 0; r < 4; ++r)
            *(uint4*)&vt[0][(vd0 + r * 32) * VTS + vc * 8] = vpre[r];
        // prefetch tile 1 (ntiles >= 2 always)
        const unsigned short* krow1 =
            kb + ((size_t)(BK + skey) * NKVH + kvh) * HD + sc * 8;
        #pragma unroll
        for (int r = 0; r < 4; ++r) kpre[r] = *(const uint4*)(krow1 + r * 32);
        const unsigned short* vtile1 = vtile0 + (size_t)HD * 64;
        #pragma unroll
        for (int r = 0; r < 4; ++r)
            vpre[r] = *(const uint4*)(vtile1 + (size_t)t * 8 + r * 2048);
    }

    for (int it = 0; it < ntiles; ++it) {
        const int j0  = it * BK;
        const int buf = it & 1;
        __syncthreads();   // buf[it] writes visible; buf[it+1] readers done

        if (it + 1 < ntiles) {
            const int nb = buf ^ 1;
            #pragma unroll
            for (int r = 0; r < 4; ++r)
                *(uint4*)&ks[nb][skey * KSS + sc * 8 + r * 32] = kpre[r];
            #pragma unroll
            for (int r = 0; r < 4; ++r)
                *(uint4*)&vt[nb][(vd0 + r * 32) * VTS + vc * 8] = vpre[r];
            if (it + 2 < ntiles) {
                const int j2 = j0 + 2 * BK;
                const unsigned short* krow =
                    kb + ((size_t)(j2 + skey) * NKVH + kvh) * HD + sc * 8;
                #pragma unroll
                for (int r = 0; r < 4; ++r) kpre[r] = *(const uint4*)(krow + r * 32);
                const unsigned short* vtile = vtile0 + (size_t)(it + 2) * HD * 64;
                #pragma unroll
                for (int r = 0; r < 4; ++r)
                    vpre[r] = *(const uint4*)(vtile + (size_t)t * 8 + r * 2048);
            }
        }

        if (j0 > wqmax) continue;   // tile fully masked for this wave
        const unsigned short* ksc = ks[buf];
        const unsigned short* vtc = vt[buf];

        // ---- S^T = K Q^T (scores already in log2 units) ----
        float16 st0, st1;
        #pragma unroll
        for (int i = 0; i < 16; ++i) { st0[i] = 0.f; st1[i] = 0.f; }
        #pragma unroll
        for (int k0 = 0; k0 < 8; ++k0) {
            const short8 a0 = *(const short8*)&ksc[ln * KSS + k0 * 16 + half * 8];
            const short8 a1 = *(const short8*)&ksc[(32 + ln) * KSS + k0 * 16 + half * 8];
            st0 = __builtin_amdgcn_mfma_f32_32x32x16_bf16(a0, qf[k0], st0, 0, 0, 0);
            st1 = __builtin_amdgcn_mfma_f32_32x32x16_bf16(a1, qf[k0], st1, 0, 0, 0);
        }

        // ---- mask + per-lane online softmax (base-2) ----
        const bool need_mask = (j0 + BK - 1) > wq0;
        float mt = -1e30f;
        if (need_mask) {
            #pragma unroll
            for (int r = 0; r < 16; ++r) {
                const int kl = (r & 3) + 8 * (r >> 2) + 4 * half;
                if (j0 + kl > qrow)      st0[r] = -1e30f;
                if (j0 + 32 + kl > qrow) st1[r] = -1e30f;
                mt = fmaxf(mt, fmaxf(st0[r], st1[r]));
            }
        } else {
            #pragma unroll
            for (int r = 0; r < 16; ++r)
                mt = fmaxf(mt, fmaxf(st0[r], st1[r]));
        }
        mt = fmaxf(mt, __shfl_xor(mt, 32, 64));
        const float mn = fmaxf(m_run, mt);
        float sm = 0.f;
        #pragma unroll
        for (int r = 0; r < 16; ++r) {
            const float e0 = exp2f(st0[r] - mn);
            const float e1 = exp2f(st1[r] - mn);
            st0[r] = e0; st1[r] = e1;
            sm += e0 + e1;
        }
        sm += __shfl_xor(sm, 32, 64);
        const float alpha = exp2f(m_run - mn);
        m_run = mn;
        l_run = l_run * alpha + sm;
        if (half == 0) alf[w][ln] = alpha;

        // ---- P C-layout -> A-layout in-register ----
        const short8 p0 = pchunk(st0, 0, half);
        const short8 p1 = pchunk(st0, 1, half);
        const short8 p2 = pchunk(st1, 0, half);
        const short8 p3 = pchunk(st1, 1, half);

        // ---- rescale O ----
        #pragma unroll
        for (int r = 0; r < 16; ++r) {
            const int rl = (r & 3) + 8 * (r >> 2) + 4 * half;
            const float ar = alf[w][rl];
            o0[r] *= ar; o1[r] *= ar; o2[r] *= ar; o3[r] *= ar;
        }

        // ---- PV ----
        #define PVSTEP(pp, kc)                                                        \
        {                                                                             \
            const short8 bv0 = *(const short8*)&vtc[(ln)      * VTS + (kc) * 16 + half * 8]; \
            const short8 bv1 = *(const short8*)&vtc[(32 + ln) * VTS + (kc) * 16 + half * 8]; \
            const short8 bv2 = *(const short8*)&vtc[(64 + ln) * VTS + (kc) * 16 + half * 8]; \
            const short8 bv3 = *(const short8*)&vtc[(96 + ln) * VTS + (kc) * 16 + half * 8]; \
            o0 = __builtin_amdgcn_mfma_f32_32x32x16_bf16(pp, bv0, o0, 0, 0, 0);       \
            o1 = __builtin_amdgcn_mfma_f32_32x32x16_bf16(pp, bv1, o1, 0, 0, 0);       \
            o2 = __builtin_amdgcn_mfma_f32_32x32x16_bf16(pp, bv2, o2, 0, 0, 0);       \
            o3 = __builtin_amdgcn_mfma_f32_32x32x16_bf16(pp, bv3, o3, 0, 0, 0);       \
        }
        PVSTEP(p0, 0)
        PVSTEP(p1, 1)
        PVSTEP(p2, 2)
        PVSTEP(p3, 3)
        #undef PVSTEP
    }

    // ---- epilogue ----
    if (half == 0) alf[w][ln] = l_run;
    __builtin_amdgcn_s_waitcnt(0);
    #pragma unroll
    for (int r = 0; r < 16; ++r) {
        const int rl = (r & 3) + 8 * (r >> 2) + 4 * half;
        const float inv = 1.f / alf[w][rl];
        float* orow = out + ((size_t)(wq0 + rl) * NH + h) * HD;
        orow[ln]      = o0[r] * inv;
        orow[32 + ln] = o1[r] * inv;
        orow[64 + ln] = o2[r] * inv;
        orow[96 + ln] = o3[r] * inv;
    }
}

// ---- fallback (round-4 kernel, no workspace needed) ----
__global__ __launch_bounds__(256, 2)
void attn_fwd_fb(const float* __restrict__ q,
                 const float* __restrict__ k,
                 const float* __restrict__ v,
                 float* __restrict__ out)
{
    __shared__ unsigned short ks[BK * KSS];
    __shared__ unsigned short vt[HD * VTS];
    __shared__ unsigned short ps[4][32 * PSS];
    __shared__ float          alf[4][32];

    const int t    = threadIdx.x;
    const int w    = t >> 6;
    const int lane = t & 63;
    const int ln   = lane & 31;
    const int half = lane >> 5;
    const int h    = blockIdx.y;
    const int kvh  = h >> 2;
    const int q0   = blockIdx.x * BQ;
    const int wq0  = q0 + w * 32;
    const int qrow = wq0 + ln;

    short8 qf[8];
    {
        const float* qr = q + ((size_t)qrow * NH + h) * HD;
        #pragma unroll
        for (int k0 = 0; k0 < 8; ++k0) {
            const float* p4 = qr + k0 * 16 + half * 8;
            const float4 a = *(const float4*)(p4);
            const float4 b = *(const float4*)(p4 + 4);
            uint4v uu;
            uu.x = f2bf2(a.x, a.y);
            uu.y = f2bf2(a.z, a.w);
            uu.z = f2bf2(b.x, b.y);
            uu.w = f2bf2(b.z, b.w);
            qf[k0] = __builtin_bit_cast(short8, uu);
        }
    }

    float16 o0, o1, o2, o3;
    #pragma unroll
    for (int i = 0; i < 16; ++i) { o0[i] = 0.f; o1[i] = 0.f; o2[i] = 0.f; o3[i] = 0.f; }
    float m_run = -1e30f, l_run = 0.f;
    const int ntiles = (q0 + BQ) / BK;
    const int wqmax  = wq0 + 31;

    for (int it = 0; it < ntiles; ++it) {
        const int j0 = it * BK;
        __syncthreads();
        {
            const int key = t >> 2;
            const int db  = (t & 3) * 4;
            const float* kr = k + ((size_t)(j0 + key) * NKVH + kvh) * HD;
            #pragma unroll
            for (int r2 = 0; r2 < 8; ++r2) {
                const int d = db + r2 * 16;
                const float4 a = *(const float4*)(kr + d);
                *(unsigned int*)&ks[key * KSS + d]     = f2bf2(a.x, a.y);
                *(unsigned int*)&ks[key * KSS + d + 2] = f2bf2(a.z, a.w);
            }
        }
        {
            const int kp = (t & 31) * 2;
            const int db = (t >> 5) * 4;
            const float* vr0 = v + ((size_t)(j0 + kp) * NKVH + kvh) * HD;
            const float* vr1 = vr0 + NKVH * HD;
            #pragma unroll
            for (int r2 = 0; r2 < 4; ++r2) {
                const int d = db + r2 * 32;
                const float4 a = *(const float4*)(vr0 + d);
                const float4 b = *(const float4*)(vr1 + d);
                *(unsigned int*)&vt[(d + 0) * VTS + kp] = f2bf2(a.x, b.x);
                *(unsigned int*)&vt[(d + 1) * VTS + kp] = f2bf2(a.y, b.y);
                *(unsigned int*)&vt[(d + 2) * VTS + kp] = f2bf2(a.z, b.z);
                *(unsigned int*)&vt[(d + 3) * VTS + kp] = f2bf2(a.w, b.w);
            }
        }
        __syncthreads();
        if (j0 > wqmax) continue;

        float16 st0, st1;
        #pragma unroll
        for (int i = 0; i < 16; ++i) { st0[i] = 0.f; st1[i] = 0.f; }
        #pragma unroll
        for (int k0 = 0; k0 < 8; ++k0) {
            const short8 a0 = *(const short8*)&ks[ln * KSS + k0 * 16 + half * 8];
            const short8 a1 = *(const short8*)&ks[(32 + ln) * KSS + k0 * 16 + half * 8];
            st0 = __builtin_amdgcn_mfma_f32_32x32x16_bf16(a0, qf[k0], st0, 0, 0, 0);
            st1 = __builtin_amdgcn_mfma_f32_32x32x16_bf16(a1, qf[k0], st1, 0, 0, 0);
        }
        const bool need_mask = (j0 + BK - 1) > wq0;
        float mt = -1e30f;
        #pragma unroll
        for (int r = 0; r < 16; ++r) {
            const int kl = (r & 3) + 8 * (r >> 2) + 4 * half;
            float a0 = st0[r] * SCALE;
            float a1 = st1[r] * SCALE;
            if (need_mask) {
                if (j0 + kl > qrow)      a0 = -1e30f;
                if (j0 + 32 + kl > qrow) a1 = -1e30f;
            }
            st0[r] = a0; st1[r] = a1;
            mt = fmaxf(mt, fmaxf(a0, a1));
        }
        mt = fmaxf(mt, __shfl_xor(mt, 32, 64));
        const float mn = fmaxf(m_run, mt);
        float sm = 0.f;
        #pragma unroll
        for (int r = 0; r < 16; ++r) {
            const float e0 = __expf(st0[r] - mn);
            const float e1 = __expf(st1[r] - mn);
            st0[r] = e0; st1[r] = e1;
            sm += e0 + e1;
        }
        sm += __shfl_xor(sm, 32, 64);
        const float alpha = __expf(m_run - mn);
        m_run = mn;
        l_run = l_run * alpha + sm;

        unsigned short* psw = ps[w];
        #pragma unroll
        for (int r = 0; r < 16; r += 2) {
            const int kl = (r & 3) + 8 * (r >> 2) + 4 * half;
            *(unsigned int*)&psw[ln * PSS + kl]      = f2bf2(st0[r], st0[r + 1]);
            *(unsigned int*)&psw[ln * PSS + 32 + kl] = f2bf2(st1[r], st1[r + 1]);
        }
        if (half == 0) alf[w][ln] = alpha;
        #pragma unroll
        for (int r = 0; r < 16; ++r) {
            const int rl = (r & 3) + 8 * (r >> 2) + 4 * half;
            const float ar = alf[w][rl];
            o0[r] *= ar; o1[r] *= ar; o2[r] *= ar; o3[r] *= ar;
        }
        short8 af[4];
        #pragma unroll
        for (int kc = 0; kc < 4; ++kc)
            af[kc] = *(const short8*)&psw[ln * PSS + kc * 16 + half * 8];
        #pragma unroll
        for (int kc = 0; kc < 4; ++kc) {
            const short8 bv0 = *(const short8*)&vt[(ln)      * VTS + kc * 16 + half * 8];
            const short8 bv1 = *(const short8*)&vt[(32 + ln) * VTS + kc * 16 + half * 8];
            const short8 bv2 = *(const short8*)&vt[(64 + ln) * VTS + kc * 16 + half * 8];
            const short8 bv3 = *(const short8*)&vt[(96 + ln) * VTS + kc * 16 + half * 8];
            o0 = __builtin_amdgcn_mfma_f32_32x32x16_bf16(af[kc], bv0, o0, 0, 0, 0);
            o1 = __builtin_amdgcn_mfma_f32_32x32x16_bf16(af[kc], bv1, o1, 0, 0, 0);
            o2 = __builtin_amdgcn_mfma_f32_32x32x16_bf16(af[kc], bv2, o2, 0, 0, 0);
            o3 = __builtin_amdgcn_mfma_f32_32x32x16_bf16(af[kc], bv3, o3, 0, 0, 0);
        }
    }

    if (half == 0) alf[w][ln] = l_run;
    __builtin_amdgcn_s_waitcnt(0);
    #pragma unroll
    for (int r = 0; r < 16; ++r) {
        const int rl = (r & 3) + 8 * (r >> 2) + 4 * half;
        const float inv = 1.f / alf[w][rl];
        float* orow = out + ((size_t)(wq0 + rl) * NH + h) * HD;
        orow[ln]      = o0[r] * inv;
        orow[32 + ln] = o1[r] * inv;
        orow[64 + ln] = o2[r] * inv;
        orow[96 + ln] = o3[r] * inv;
    }
}

extern "C" void kernel_launch(void* const* d_in, const int* in_sizes, int n_in,
                              void* d_out, int out_size, void* d_ws, size_t ws_size,
                              hipStream_t stream) {
    const float* q = (const float*)d_in[0];
    const float* k = (const float*)d_in[1];
    const float* v = (const float*)d_in[2];
    float* out = (float*)d_out;
    if (ws_size >= (size_t)WS_NEED) {
        unsigned short* kb  = (unsigned short*)d_ws;
        unsigned short* vtw = kb + KB_ELEMS;
        cvt_k<<<KB_ELEMS / (256 * 4), 256, 0, stream>>>(k, kb);
        cvt_v<<<NKVH * 32, 256, 0, stream>>>(v, vtw);
        attn_fwd2<<<512, 256, 0, stream>>>(q, kb, vtw, out);
    } else {
        attn_fwd_fb<<<dim3(SEQ / BQ, NH), 256, 0, stream>>>(q, k, v, out);
    }
}